// Round 3
// baseline (241.768 us; speedup 1.0000x reference)
//
#include <hip/hip_runtime.h>

#define EMBED  128
#define BATCH  64
#define SEQLEN 2048

// ---------------------------------------------------------------------------
// Fused CBOW kernel (last-block-done pattern).
// grid.x = BATCH * SPLIT, block = 128 threads.
// Phase 1: block (b,s) sums CHUNK=SEQLEN/SPLIT consecutive tokens of batch b
//          into partial[b][s][0..127] (deterministic per-block sums).
// Phase 2: the block that draws ticket SPLIT-1 for batch b (after a device-
//          scope release fence + atomicAdd) acquires, reduces the SPLIT
//          partials in fixed s-order (deterministic), applies the boundary
//          corrections, and writes out[b][4][128].
// cnt[] must be zeroed before launch (hipMemsetAsync in kernel_launch).
// ---------------------------------------------------------------------------
template <int SPLIT>
__global__ __launch_bounds__(128) void cbow_fused_kernel(
    const int* __restrict__ x, const float* __restrict__ emb,
    float* __restrict__ partial, unsigned int* __restrict__ cnt,
    float* __restrict__ out) {
    constexpr int CHUNK = SEQLEN / SPLIT;
    const int blk = blockIdx.x;
    const int b = blk / SPLIT;
    const int s = blk - b * SPLIT;
    const int tid = threadIdx.x;
    const int c = tid & 31;   // float4 column within the 128-float row
    const int r = tid >> 5;   // row group 0..3

    __shared__ int toks[CHUNK];
    const int base = b * SEQLEN + s * CHUNK;
    for (int i = tid; i < CHUNK; i += 128) toks[i] = x[base + i];
    __syncthreads();

    constexpr int ITERS = CHUNK / 4;  // gathers per thread
    float4 a0 = make_float4(0.f, 0.f, 0.f, 0.f);
    float4 a1 = make_float4(0.f, 0.f, 0.f, 0.f);
    const float* embc = emb + c * 4;
#pragma unroll
    for (int it = 0; it < ITERS; it += 2) {
        const float4 v0 = *reinterpret_cast<const float4*>(
            embc + (size_t)toks[r + 4 * it] * EMBED);
        const float4 v1 = *reinterpret_cast<const float4*>(
            embc + (size_t)toks[r + 4 * (it + 1)] * EMBED);
        a0.x += v0.x; a0.y += v0.y; a0.z += v0.z; a0.w += v0.w;
        a1.x += v1.x; a1.y += v1.y; a1.z += v1.z; a1.w += v1.w;
    }
    a0.x += a1.x; a0.y += a1.y; a0.z += a1.z; a0.w += a1.w;

    __shared__ float psum[4][EMBED];
    psum[r][c * 4 + 0] = a0.x;
    psum[r][c * 4 + 1] = a0.y;
    psum[r][c * 4 + 2] = a0.z;
    psum[r][c * 4 + 3] = a0.w;
    __syncthreads();

    const float ssum = psum[0][tid] + psum[1][tid] + psum[2][tid] + psum[3][tid];
    partial[((size_t)b * SPLIT + s) * EMBED + tid] = ssum;

    // ---- release: make partial visible device-wide, then take a ticket ----
    __threadfence();
    __shared__ unsigned int ticket;
    if (tid == 0) ticket = atomicAdd(&cnt[b], 1u);
    __syncthreads();
    if (ticket != SPLIT - 1) return;

    // ---- last block for batch b: acquire, reduce, correct, write ----
    __threadfence();
    const float* p = partial + (size_t)b * SPLIT * EMBED + tid;
    float s0 = 0.f, s1 = 0.f, s2 = 0.f, s3 = 0.f;
#pragma unroll
    for (int q = 0; q < SPLIT; q += 4) {
        s0 += p[(size_t)(q + 0) * EMBED];
        s1 += p[(size_t)(q + 1) * EMBED];
        s2 += p[(size_t)(q + 2) * EMBED];
        s3 += p[(size_t)(q + 3) * EMBED];
    }
    const float S = (s0 + s1) + (s2 + s3);

    const int e = tid;
    const float e0 = emb[e];  // emb[token 0]
    const int t0  = x[b * SEQLEN + 0];
    const int t1  = x[b * SEQLEN + 1];
    const int tl2 = x[b * SEQLEN + SEQLEN - 2];
    const int tl1 = x[b * SEQLEN + SEQLEN - 1];
    const float v0  = emb[(size_t)t0  * EMBED + e];
    const float v1  = emb[(size_t)t1  * EMBED + e];
    const float vl2 = emb[(size_t)tl2 * EMBED + e];
    const float vl1 = emb[(size_t)tl1 * EMBED + e];

    float* ob = out + (size_t)b * 4 * EMBED;
    ob[0 * EMBED + e] = S - vl1 + e0;              // offset -1: 1 OOB
    ob[1 * EMBED + e] = S - vl2 - vl1 + 2.f * e0;  // offset -2: 2 OOB
    ob[2 * EMBED + e] = S - v0 + e0;               // offset +1: 1 OOB
    ob[3 * EMBED + e] = S - v0 - v1 + 2.f * e0;    // offset +2: 2 OOB
}

extern "C" void kernel_launch(void* const* d_in, const int* in_sizes, int n_in,
                              void* d_out, int out_size, void* d_ws, size_t ws_size,
                              hipStream_t stream) {
    const int*   x   = (const int*)d_in[0];
    const float* emb = (const float*)d_in[1];
    float*       out = (float*)d_out;

    unsigned int* cnt     = (unsigned int*)d_ws;
    float*        partial = (float*)((char*)d_ws + 1024);  // 16B-aligned

    // Zero the 64 per-batch ticket counters (graph-capture-safe async memset).
    hipMemsetAsync(d_ws, 0, BATCH * sizeof(unsigned int), stream);

    // Largest SPLIT whose partial buffer fits in d_ws (64 needs ~2 MiB).
    const size_t need64 = 1024 + (size_t)BATCH * 64 * EMBED * sizeof(float);
    const size_t need32 = 1024 + (size_t)BATCH * 32 * EMBED * sizeof(float);
    if (ws_size >= need64) {
        cbow_fused_kernel<64><<<dim3(BATCH * 64), dim3(128), 0, stream>>>(
            x, emb, partial, cnt, out);
    } else if (ws_size >= need32) {
        cbow_fused_kernel<32><<<dim3(BATCH * 32), dim3(128), 0, stream>>>(
            x, emb, partial, cnt, out);
    } else {
        cbow_fused_kernel<16><<<dim3(BATCH * 16), dim3(128), 0, stream>>>(
            x, emb, partial, cnt, out);
    }
}

// Round 4
// 15.311 us; speedup vs baseline: 15.7901x; 15.7901x over previous
//
#include <hip/hip_runtime.h>

#define EMBED  128
#define BATCH  64
#define SEQLEN 2048
#define NSLICE 4              // slices of the 128-float row
#define SLICEF 32             // floats per slice (128 B)
#define BLOCK  1024
#define NROWG  (BLOCK / 8)    // 128 row-groups (8 lanes x float4 = one slice)
#define TOKPG  (SEQLEN / NROWG)  // 16 tokens per row-group

__device__ __forceinline__ float4 f4add(const float4 a, const float4 b) {
    return make_float4(a.x + b.x, a.y + b.y, a.z + b.z, a.w + b.w);
}
__device__ __forceinline__ float4 f4sub(const float4 a, const float4 b) {
    return make_float4(a.x - b.x, a.y - b.y, a.z - b.z, a.w - b.w);
}

// ---------------------------------------------------------------------------
// One-pass CBOW: block (b, slice) sums ALL tokens of batch b over a 32-float
// slice of the embedding row, then applies boundary corrections and writes
// its slice of out[b][4][128]. No cross-block communication, no fences.
//   c = tid & 7  -> float4 within the slice (8 lanes * 16 B = 128 B segment)
//   r = tid >> 3 -> row-group 0..127, handles tokens r, r+128, ... (16 each)
// ---------------------------------------------------------------------------
__global__ __launch_bounds__(BLOCK) void cbow_onepass_kernel(
    const int* __restrict__ x, const float* __restrict__ emb,
    float* __restrict__ out) {
    const int b   = blockIdx.x >> 2;
    const int sl  = blockIdx.x & 3;
    const int tid = threadIdx.x;
    const int c   = tid & 7;
    const int r   = tid >> 3;

    __shared__ int    toks[SEQLEN];      // 8 KiB
    __shared__ float4 psum[NROWG][8];    // 8 KiB

    // Stage the batch's tokens: 1024 threads x int2 = 2048 ints, coalesced.
    reinterpret_cast<int2*>(toks)[tid] =
        reinterpret_cast<const int2*>(x + b * SEQLEN)[tid];
    __syncthreads();

    const float* embs = emb + sl * SLICEF + c * 4;
    float4 a0 = make_float4(0.f, 0.f, 0.f, 0.f);
    float4 a1 = a0, a2 = a0, a3 = a0;
#pragma unroll
    for (int it = 0; it < TOKPG; it += 4) {
        const float4 v0 = *reinterpret_cast<const float4*>(
            embs + (size_t)toks[r + NROWG * (it + 0)] * EMBED);
        const float4 v1 = *reinterpret_cast<const float4*>(
            embs + (size_t)toks[r + NROWG * (it + 1)] * EMBED);
        const float4 v2 = *reinterpret_cast<const float4*>(
            embs + (size_t)toks[r + NROWG * (it + 2)] * EMBED);
        const float4 v3 = *reinterpret_cast<const float4*>(
            embs + (size_t)toks[r + NROWG * (it + 3)] * EMBED);
        a0 = f4add(a0, v0);
        a1 = f4add(a1, v1);
        a2 = f4add(a2, v2);
        a3 = f4add(a3, v3);
    }
    psum[r][c] = f4add(f4add(a0, a1), f4add(a2, a3));
    __syncthreads();

    // Tree-reduce the 128 row-group partials (fixed order -> deterministic).
#pragma unroll
    for (int s = NROWG / 2; s >= 1; s >>= 1) {
        if (r < s) psum[r][c] = f4add(psum[r][c], psum[r + s][c]);
        __syncthreads();
    }

    // Epilogue: 32 threads, (o = output row 0..3) x (c = float4 chunk).
    if (tid < 32) {
        const int o = tid >> 3;
        const float4 S = psum[0][c];
        const int t0  = toks[0];
        const int t1  = toks[1];
        const int tl2 = toks[SEQLEN - 2];
        const int tl1 = toks[SEQLEN - 1];
        const float4 e0  = *reinterpret_cast<const float4*>(embs);  // token 0
        const float4 v0  = *reinterpret_cast<const float4*>(embs + (size_t)t0  * EMBED);
        const float4 v1  = *reinterpret_cast<const float4*>(embs + (size_t)t1  * EMBED);
        const float4 vl2 = *reinterpret_cast<const float4*>(embs + (size_t)tl2 * EMBED);
        const float4 vl1 = *reinterpret_cast<const float4*>(embs + (size_t)tl1 * EMBED);

        float4 res = f4add(S, e0);
        if (o == 0) {
            res = f4sub(res, vl1);                           // offset -1
        } else if (o == 1) {
            res = f4add(f4sub(f4sub(res, vl1), vl2), e0);    // offset -2
        } else if (o == 2) {
            res = f4sub(res, v0);                            // offset +1
        } else {
            res = f4add(f4sub(f4sub(res, v0), v1), e0);      // offset +2
        }

        *reinterpret_cast<float4*>(
            out + ((size_t)b * 4 + o) * EMBED + sl * SLICEF + c * 4) = res;
    }
}

extern "C" void kernel_launch(void* const* d_in, const int* in_sizes, int n_in,
                              void* d_out, int out_size, void* d_ws, size_t ws_size,
                              hipStream_t stream) {
    const int*   x   = (const int*)d_in[0];
    const float* emb = (const float*)d_in[1];
    float*       out = (float*)d_out;

    cbow_onepass_kernel<<<dim3(BATCH * NSLICE), dim3(BLOCK), 0, stream>>>(
        x, emb, out);
}

// Round 5
// 14.215 us; speedup vs baseline: 17.0085x; 1.0772x over previous
//
#include <hip/hip_runtime.h>

#define EMBED  128
#define BATCH  64
#define SEQLEN 2048
#define NSLICE 4              // slices of the 128-float row
#define SLICEF 32             // floats per slice (128 B)
#define BLOCK  1024
#define NROWG  (BLOCK / 8)    // 128 row-groups (8 lanes x float4 = one slice)
#define TOKPG  (SEQLEN / NROWG)  // 16 tokens per row-group

__device__ __forceinline__ float4 f4add(const float4 a, const float4 b) {
    return make_float4(a.x + b.x, a.y + b.y, a.z + b.z, a.w + b.w);
}
__device__ __forceinline__ float4 f4sub(const float4 a, const float4 b) {
    return make_float4(a.x - b.x, a.y - b.y, a.z - b.z, a.w - b.w);
}
__device__ __forceinline__ float4 f4shfl_xor(const float4 v, int mask) {
    return make_float4(__shfl_xor(v.x, mask), __shfl_xor(v.y, mask),
                       __shfl_xor(v.z, mask), __shfl_xor(v.w, mask));
}

// ---------------------------------------------------------------------------
// One-pass CBOW with slice->XCD affinity.
// grid.x = 256; logical block (b, sl) remapped so slice sl runs only on
// XCDs {2sl, 2sl+1} (blockIdx%8 selects the XCD on MI355X):
//   idx = (b>>1)<<3 | sl<<1 | (b&1)   (bijective on [0,256))
// Each block sums all 2048 tokens of batch b over a 32-float slice, then
// applies boundary corrections and writes its slice of out[b][4][128].
//   c = tid & 7  -> float4 within the slice (8 lanes * 16 B = 128 B segment)
//   r = tid >> 3 -> row-group 0..127, tokens r, r+128, ... (16 each)
// Reduce: 3 shfl_xor rounds in-wave (8 row-groups/wave) + 1 LDS round
// across the 16 waves -> 2 barriers instead of a 7-barrier tree.
// ---------------------------------------------------------------------------
__global__ __launch_bounds__(BLOCK) void cbow_onepass_kernel(
    const int* __restrict__ x, const float* __restrict__ emb,
    float* __restrict__ out) {
    const int idx = blockIdx.x;
    const int sl  = (idx & 7) >> 1;
    const int b   = ((idx >> 3) << 1) | (idx & 1);
    const int tid = threadIdx.x;
    const int c   = tid & 7;
    const int r   = tid >> 3;
    const int w   = tid >> 6;   // wave 0..15
    const int ln  = tid & 63;   // lane

    const float* embs = emb + sl * SLICEF + c * 4;

    // --- Hoisted epilogue loads: issue early, consumed after final barrier.
    float4 e0v, v0v, v1v, vl2v, vl1v;
    if (tid < 32) {
        const int ec  = tid & 7;
        const float* embe = emb + sl * SLICEF + ec * 4;
        const int t0  = x[b * SEQLEN + 0];
        const int t1  = x[b * SEQLEN + 1];
        const int tl2 = x[b * SEQLEN + SEQLEN - 2];
        const int tl1 = x[b * SEQLEN + SEQLEN - 1];
        e0v  = *reinterpret_cast<const float4*>(embe);
        v0v  = *reinterpret_cast<const float4*>(embe + (size_t)t0  * EMBED);
        v1v  = *reinterpret_cast<const float4*>(embe + (size_t)t1  * EMBED);
        vl2v = *reinterpret_cast<const float4*>(embe + (size_t)tl2 * EMBED);
        vl1v = *reinterpret_cast<const float4*>(embe + (size_t)tl1 * EMBED);
    }

    __shared__ int    toks[SEQLEN];      // 8 KiB
    __shared__ float4 psum[16][8];       // 2 KiB (per-wave partials)

    // Stage the batch's tokens: 1024 threads x int2 = 2048 ints, coalesced.
    reinterpret_cast<int2*>(toks)[tid] =
        reinterpret_cast<const int2*>(x + b * SEQLEN)[tid];
    __syncthreads();

    float4 a0 = make_float4(0.f, 0.f, 0.f, 0.f);
    float4 a1 = a0, a2 = a0, a3 = a0;
#pragma unroll
    for (int it = 0; it < TOKPG; it += 4) {
        const float4 v0 = *reinterpret_cast<const float4*>(
            embs + (size_t)toks[r + NROWG * (it + 0)] * EMBED);
        const float4 v1 = *reinterpret_cast<const float4*>(
            embs + (size_t)toks[r + NROWG * (it + 1)] * EMBED);
        const float4 v2 = *reinterpret_cast<const float4*>(
            embs + (size_t)toks[r + NROWG * (it + 2)] * EMBED);
        const float4 v3 = *reinterpret_cast<const float4*>(
            embs + (size_t)toks[r + NROWG * (it + 3)] * EMBED);
        a0 = f4add(a0, v0);
        a1 = f4add(a1, v1);
        a2 = f4add(a2, v2);
        a3 = f4add(a3, v3);
    }
    float4 acc = f4add(f4add(a0, a1), f4add(a2, a3));

    // In-wave reduce across the 8 row-groups (lane bits 3..5).
    acc = f4add(acc, f4shfl_xor(acc, 8));
    acc = f4add(acc, f4shfl_xor(acc, 16));
    acc = f4add(acc, f4shfl_xor(acc, 32));
    if (ln < 8) psum[w][c] = acc;   // lane ln==c here
    __syncthreads();

    // Wave 0 reduces the 16 per-wave partials.
    if (w == 0) {
        const int g = ln >> 3;  // 0..7
        float4 t = f4add(psum[g][c], psum[g + 8][c]);
        t = f4add(t, f4shfl_xor(t, 8));
        t = f4add(t, f4shfl_xor(t, 16));
        t = f4add(t, f4shfl_xor(t, 32));
        if (ln < 8) psum[0][c] = t;
    }
    __syncthreads();

    // Epilogue: 32 threads, (o = output row 0..3) x (c = float4 chunk).
    if (tid < 32) {
        const int o = tid >> 3;
        const float4 S = psum[0][c];
        float4 res = f4add(S, e0v);
        if (o == 0) {
            res = f4sub(res, vl1v);                            // offset -1
        } else if (o == 1) {
            res = f4add(f4sub(f4sub(res, vl1v), vl2v), e0v);   // offset -2
        } else if (o == 2) {
            res = f4sub(res, v0v);                             // offset +1
        } else {
            res = f4add(f4sub(f4sub(res, v0v), v1v), e0v);     // offset +2
        }
        *reinterpret_cast<float4*>(
            out + ((size_t)b * 4 + o) * EMBED + sl * SLICEF + c * 4) = res;
    }
}

extern "C" void kernel_launch(void* const* d_in, const int* in_sizes, int n_in,
                              void* d_out, int out_size, void* d_ws, size_t ws_size,
                              hipStream_t stream) {
    const int*   x   = (const int*)d_in[0];
    const float* emb = (const float*)d_in[1];
    float*       out = (float*)d_out;

    cbow_onepass_kernel<<<dim3(BATCH * NSLICE), dim3(BLOCK), 0, stream>>>(
        x, emb, out);
}

// Round 6
// 14.118 us; speedup vs baseline: 17.1246x; 1.0068x over previous
//
#include <hip/hip_runtime.h>

#define EMBED  128
#define BATCH  64
#define SEQLEN 2048
#define NSLICE 4                 // slices of the 128-float row
#define SLICEF 32                // floats per slice (128 B)
#define BLOCK  512
#define NROWG  (BLOCK / 8)       // 64 row-groups (8 lanes x float4 = one slice)
#define TOKPG  (SEQLEN / NROWG)  // 32 tokens per row-group

__device__ __forceinline__ float4 f4add(const float4 a, const float4 b) {
    return make_float4(a.x + b.x, a.y + b.y, a.z + b.z, a.w + b.w);
}
__device__ __forceinline__ float4 f4sub(const float4 a, const float4 b) {
    return make_float4(a.x - b.x, a.y - b.y, a.z - b.z, a.w - b.w);
}
__device__ __forceinline__ float4 f4shfl_xor(const float4 v, int mask) {
    return make_float4(__shfl_xor(v.x, mask), __shfl_xor(v.y, mask),
                       __shfl_xor(v.z, mask), __shfl_xor(v.w, mask));
}

// ---------------------------------------------------------------------------
// One-pass CBOW, barrier-free front end.
// grid.x = 256; logical block (b, sl) remapped so slice sl runs only on
// XCDs {2sl, 2sl+1}: idx = (b>>1)<<3 | sl<<1 | (b&1).
// Each block sums all 2048 tokens of batch b over a 32-float slice.
//   c = tid & 7  -> float4 within the slice (8 lanes * 16 B = 128 B segment)
//   r = tid >> 3 -> row-group 0..63, owns tokens r, r+64, ... (32 each)
// Tokens are loaded straight from global (uniform across the 8-lane group,
// L1-broadcast) -- no LDS staging, no front barrier. 8 independent float4
// accumulators keep up to ~16-32 gathers in flight per lane.
// Reduce: 3 shfl_xor rounds in-wave -> psum[8][8] -> 1 barrier -> wave-0
// butterfly (every lane ends with its column total) -> 32-lane epilogue.
// ---------------------------------------------------------------------------
__global__ __launch_bounds__(BLOCK) void cbow_onepass_kernel(
    const int* __restrict__ x, const float* __restrict__ emb,
    float* __restrict__ out) {
    const int idx = blockIdx.x;
    const int sl  = (idx & 7) >> 1;
    const int b   = ((idx >> 3) << 1) | (idx & 1);
    const int tid = threadIdx.x;
    const int c   = tid & 7;
    const int r   = tid >> 3;   // row-group 0..63
    const int w   = tid >> 6;   // wave 0..7
    const int ln  = tid & 63;   // lane

    const int*   xb   = x + b * SEQLEN;
    const float* embs = emb + sl * SLICEF + c * 4;

    // --- Hoisted epilogue loads (lanes 0..31): issue early, use at the end.
    float4 e0v, v0v, v1v, vl2v, vl1v;
    if (tid < 32) {
        const int t0  = xb[0];
        const int t1  = xb[1];
        const int tl2 = xb[SEQLEN - 2];
        const int tl1 = xb[SEQLEN - 1];
        e0v  = *reinterpret_cast<const float4*>(embs);
        v0v  = *reinterpret_cast<const float4*>(embs + (size_t)t0  * EMBED);
        v1v  = *reinterpret_cast<const float4*>(embs + (size_t)t1  * EMBED);
        vl2v = *reinterpret_cast<const float4*>(embs + (size_t)tl2 * EMBED);
        vl1v = *reinterpret_cast<const float4*>(embs + (size_t)tl1 * EMBED);
    }

    // --- Token loads: 32 independent uniform loads per row-group.
    int tk[TOKPG];
#pragma unroll
    for (int it = 0; it < TOKPG; ++it) tk[it] = xb[r + NROWG * it];

    // --- Gather + accumulate: 8 independent accumulators, fully unrolled.
    float4 acc[8];
#pragma unroll
    for (int i = 0; i < 8; ++i) acc[i] = make_float4(0.f, 0.f, 0.f, 0.f);
#pragma unroll
    for (int it = 0; it < TOKPG; ++it) {
        const float4 v = *reinterpret_cast<const float4*>(
            embs + (size_t)tk[it] * EMBED);
        acc[it & 7] = f4add(acc[it & 7], v);
    }
    float4 s01 = f4add(acc[0], acc[1]);
    float4 s23 = f4add(acc[2], acc[3]);
    float4 s45 = f4add(acc[4], acc[5]);
    float4 s67 = f4add(acc[6], acc[7]);
    float4 a = f4add(f4add(s01, s23), f4add(s45, s67));

    // --- In-wave reduce across the 8 row-groups (lane bits 3..5).
    a = f4add(a, f4shfl_xor(a, 8));
    a = f4add(a, f4shfl_xor(a, 16));
    a = f4add(a, f4shfl_xor(a, 32));

    __shared__ float4 psum[8][8];
    if (ln < 8) psum[w][c] = a;   // lane ln == c here
    __syncthreads();

    // --- Wave 0: butterfly over the 8 per-wave partials; every lane ends
    //     holding the total for its own column c = ln & 7.
    if (w == 0) {
        const int g = ln >> 3;  // 0..7
        float4 t = psum[g & 7][c];
        t = f4add(t, f4shfl_xor(t, 8));
        t = f4add(t, f4shfl_xor(t, 16));
        t = f4add(t, f4shfl_xor(t, 32));

        // --- Epilogue: lanes 0..31, o = output row 0..3.
        if (ln < 32) {
            const int o = ln >> 3;
            float4 res = f4add(t, e0v);
            if (o == 0) {
                res = f4sub(res, vl1v);                            // offset -1
            } else if (o == 1) {
                res = f4add(f4sub(f4sub(res, vl1v), vl2v), e0v);   // offset -2
            } else if (o == 2) {
                res = f4sub(res, v0v);                             // offset +1
            } else {
                res = f4add(f4sub(f4sub(res, v0v), v1v), e0v);     // offset +2
            }
            *reinterpret_cast<float4*>(
                out + ((size_t)b * 4 + o) * EMBED + sl * SLICEF + c * 4) = res;
        }
    }
}

extern "C" void kernel_launch(void* const* d_in, const int* in_sizes, int n_in,
                              void* d_out, int out_size, void* d_ws, size_t ws_size,
                              hipStream_t stream) {
    const int*   x   = (const int*)d_in[0];
    const float* emb = (const float*)d_in[1];
    float*       out = (float*)d_out;

    cbow_onepass_kernel<<<dim3(BATCH * NSLICE), dim3(BLOCK), 0, stream>>>(
        x, emb, out);
}